// Round 3
// baseline (117.169 us; speedup 1.0000x reference)
//
#include <hip/hip_runtime.h>

#define BATCH 32768
#define FEAT 512
#define KCENT 2
#define SAMPLES_PER_WAVE 4
#define NBLOCKS (BATCH / (4 * SAMPLES_PER_WAVE))   // 2048 blocks, 4 waves each

typedef float vf4 __attribute__((ext_vector_type(4)));

// One wave (64 lanes) per 4 consecutive samples; 4 waves per 256-thread block.
// Each block contributes one atomicAdd of (block_sum / BATCH) into out[0],
// which kernel_launch zeroes via hipMemsetAsync beforehand.
__global__ __launch_bounds__(256) void mcl_fused(
    const float* __restrict__ x,
    const int* __restrict__ labels,
    const float* __restrict__ centers,
    float* __restrict__ out)
{
    const int wave = threadIdx.x >> 6;
    const int lane = threadIdx.x & 63;
    const int gw   = blockIdx.x * 4 + wave;       // global wave id
    const int base = gw * SAMPLES_PER_WAVE;       // first sample of this wave

    // coalesced label preload: lanes 0..3 fetch, broadcast later via shfl
    int labv = 0;
    if (lane < SAMPLES_PER_WAVE) labv = labels[base + lane];

    float wsum = 0.f;   // valid on lane 0

#pragma unroll
    for (int s = 0; s < SAMPLES_PER_WAVE; ++s) {
        const int lab = __shfl(labv, s, 64);
        const float* __restrict__ xrow = x + (size_t)(base + s) * FEAT;
        const float* __restrict__ c0   = centers + (size_t)lab * (KCENT * FEAT);

        float d0 = 0.f, d1 = 0.f;
#pragma unroll
        for (int j = 0; j < 2; ++j) {
            const int off = j * 256 + lane * 4;   // dense 1 KiB per instruction
            const vf4 xv = *(const vf4*)(xrow + off);
            const vf4 a  = *(const vf4*)(c0 + off);
            const vf4 b  = *(const vf4*)(c0 + FEAT + off);
            float e;
            e = xv.x - a.x; d0 += e * e;
            e = xv.y - a.y; d0 += e * e;
            e = xv.z - a.z; d0 += e * e;
            e = xv.w - a.w; d0 += e * e;
            e = xv.x - b.x; d1 += e * e;
            e = xv.y - b.y; d1 += e * e;
            e = xv.z - b.z; d1 += e * e;
            e = xv.w - b.w; d1 += e * e;
        }

        // wave-64 reduction of both candidate distances
#pragma unroll
        for (int sh = 32; sh > 0; sh >>= 1) {
            d0 += __shfl_down(d0, sh, 64);
            d1 += __shfl_down(d1, sh, 64);
        }
        if (lane == 0) wsum += fminf(d0, d1);
    }

    __shared__ float sacc[4];
    if (lane == 0) sacc[wave] = wsum;
    __syncthreads();
    if (threadIdx.x == 0) {
        const float bsum = (sacc[0] + sacc[1]) + (sacc[2] + sacc[3]);
        atomicAdd(out, bsum * (1.0f / (float)BATCH));
    }
}

extern "C" void kernel_launch(void* const* d_in, const int* in_sizes, int n_in,
                              void* d_out, int out_size, void* d_ws, size_t ws_size,
                              hipStream_t stream) {
    const float* x       = (const float*)d_in[0];
    const int*   labels  = (const int*)d_in[1];
    const float* centers = (const float*)d_in[2];
    float* out = (float*)d_out;

    hipMemsetAsync(out, 0, sizeof(float), stream);
    mcl_fused<<<NBLOCKS, 256, 0, stream>>>(x, labels, centers, out);
}

// Round 4
// 103.461 us; speedup vs baseline: 1.1325x; 1.1325x over previous
//
#include <hip/hip_runtime.h>

#define BATCH 32768
#define FEAT 512
#define KCENT 2
#define SAMPLES_PER_WAVE 4
#define NBLOCKS (BATCH / (4 * SAMPLES_PER_WAVE))   // 2048 blocks, 4 waves each

typedef float vf4 __attribute__((ext_vector_type(4)));

// One wave (64 lanes) per 4 consecutive samples; 4 waves per 256-thread block.
__global__ __launch_bounds__(256) void mcl_partial(
    const float* __restrict__ x,
    const int* __restrict__ labels,
    const float* __restrict__ centers,
    float* __restrict__ partial)
{
    const int wave = threadIdx.x >> 6;
    const int lane = threadIdx.x & 63;
    const int gw   = blockIdx.x * 4 + wave;       // global wave id
    const int base = gw * SAMPLES_PER_WAVE;       // first sample of this wave

    // coalesced label preload: lanes 0..3 fetch, broadcast later via shfl
    int labv = 0;
    if (lane < SAMPLES_PER_WAVE) labv = labels[base + lane];

    float wsum = 0.f;   // valid on lane 0

#pragma unroll
    for (int s = 0; s < SAMPLES_PER_WAVE; ++s) {
        const int lab = __shfl(labv, s, 64);
        const float* __restrict__ xrow = x + (size_t)(base + s) * FEAT;
        const float* __restrict__ c0   = centers + (size_t)lab * (KCENT * FEAT);

        float d0 = 0.f, d1 = 0.f;
#pragma unroll
        for (int j = 0; j < 2; ++j) {
            const int off = j * 256 + lane * 4;   // dense 1 KiB per instruction
            const vf4 xv = *(const vf4*)(xrow + off);
            const vf4 a  = *(const vf4*)(c0 + off);
            const vf4 b  = *(const vf4*)(c0 + FEAT + off);
            float e;
            e = xv.x - a.x; d0 += e * e;
            e = xv.y - a.y; d0 += e * e;
            e = xv.z - a.z; d0 += e * e;
            e = xv.w - a.w; d0 += e * e;
            e = xv.x - b.x; d1 += e * e;
            e = xv.y - b.y; d1 += e * e;
            e = xv.z - b.z; d1 += e * e;
            e = xv.w - b.w; d1 += e * e;
        }

        // wave-64 reduction of both candidate distances
#pragma unroll
        for (int sh = 32; sh > 0; sh >>= 1) {
            d0 += __shfl_down(d0, sh, 64);
            d1 += __shfl_down(d1, sh, 64);
        }
        if (lane == 0) wsum += fminf(d0, d1);
    }

    __shared__ float sacc[4];
    if (lane == 0) sacc[wave] = wsum;
    __syncthreads();
    if (threadIdx.x == 0)
        partial[blockIdx.x] = (sacc[0] + sacc[1]) + (sacc[2] + sacc[3]);
}

// Single block: 2048 partials, 8 independent loads/thread (one latency round).
__global__ __launch_bounds__(256) void mcl_final(
    const float* __restrict__ partial, float* __restrict__ out)
{
    float s = 0.f;
#pragma unroll
    for (int j = 0; j < NBLOCKS / 256; ++j)
        s += partial[j * 256 + threadIdx.x];
#pragma unroll
    for (int sh = 32; sh > 0; sh >>= 1) s += __shfl_down(s, sh, 64);
    __shared__ float ws[4];
    const int wave = threadIdx.x >> 6;
    const int lane = threadIdx.x & 63;
    if (lane == 0) ws[wave] = s;
    __syncthreads();
    if (threadIdx.x == 0)
        out[0] = ((ws[0] + ws[1]) + (ws[2] + ws[3])) * (1.0f / (float)BATCH);
}

extern "C" void kernel_launch(void* const* d_in, const int* in_sizes, int n_in,
                              void* d_out, int out_size, void* d_ws, size_t ws_size,
                              hipStream_t stream) {
    const float* x       = (const float*)d_in[0];
    const int*   labels  = (const int*)d_in[1];
    const float* centers = (const float*)d_in[2];
    float* out = (float*)d_out;
    float* partial = (float*)d_ws;

    mcl_partial<<<NBLOCKS, 256, 0, stream>>>(x, labels, centers, partial);
    mcl_final<<<1, 256, 0, stream>>>(partial, out);
}